// Round 12
// baseline (89.937 us; speedup 1.0000x reference)
//
#include <hip/hip_runtime.h>
#include <hip/hip_bf16.h>

// EmbeddingPredictor: B=16 T=2048 V=32000 E=512 H=4 C=3, f32 in/out.
// R12 = R11 decomposition with f32 EP (the 0.172 outlier was the bf16 score dots;
//       bit-identical failure in R4/R11 isolated it).
//   out_t = (1/12) * sum_c s_c * XW[tok_{t-2+c}] + bias,  s_c = EP[tok_{t-2+c}][c]
//  K0 prep:   Pt[3][512] f32; Wb bf16
//  K1 ep:     EP[32000][4] f32 = table @ P, f32 dots + shfl (proven numerics);
//             also warms L3 with the table for K2.
//  K2 xw:     XW = table @ W^T bf16 GEMM (64x128 tiles, reg-staged A, gload_lds B,
//             dbuf, 1 barrier/K-step), stores XW bf16.
//  K3 gather: wave-per-token: 3 EP scalars + 3 XW bf16 rows -> combine -> bias +
//             LayerNorm + swish -> f32 out. Pure streaming, no MFMA/LDS.
// ws: Pt @0 (8KB), Wb @16K (512KB), EP @1M (512KB), XW @2M (32.8MB).

#define Bq 16
#define Tq 2048
#define Eq 512
#define Cq 3
#define Hq 4
#define Vq 32000
#define Mq (Bq * Tq)
#define LN_EPS 1e-5f

typedef __attribute__((ext_vector_type(8))) short bf16x8;
typedef __attribute__((ext_vector_type(4))) float f32x4;

__device__ __forceinline__ unsigned short f2bf(float f) {
    unsigned int u = __float_as_uint(f);
    u += 0x7fffu + ((u >> 16) & 1u);   // RNE
    return (unsigned short)(u >> 16);
}
__device__ __forceinline__ float bf2f(unsigned short h) {
    return __uint_as_float(((unsigned int)h) << 16);
}
__device__ __forceinline__ unsigned int cvt_pk_bf16(float lo, float hi) {
    unsigned int r;
    asm("v_cvt_pk_bf16_f32 %0, %1, %2" : "=v"(r) : "v"(lo), "v"(hi));
    return r;   // low16 = bf16(lo), high16 = bf16(hi), RNE
}

// ---------------- K0: prep ----------------
__global__ void prep_kernel(const float* __restrict__ pos,
                            const float* __restrict__ ffn_w,
                            float* __restrict__ Pt,            // [C][512] f32
                            unsigned short* __restrict__ Wb) { // [512][512] bf16 [n][k]
    int i = blockIdx.x * blockDim.x + threadIdx.x;   // 16384 threads
    if (i < Cq * Eq) {
        int c = i / Eq, e = i % Eq;
        float s = 0.f;
#pragma unroll
        for (int h = 0; h < Hq; ++h) s += pos[(h * Eq + e) * Cq + c];
        Pt[i] = s;
    }
    for (int j = i; j < Eq * Eq; j += 16384) Wb[j] = f2bf(ffn_w[j]);
}

// ---------------- K1: EP = table @ P (f32 dots, proven numerics) ----------------
// grid = V/4 = 8000 blocks, 256 threads, one wave per vocab row.
__global__ __launch_bounds__(256) void ep_kernel(const float* __restrict__ tbl,
                                                 const float* __restrict__ Pt,
                                                 float* __restrict__ EP) {
    const int wave = threadIdx.x >> 6;
    const int lane = threadIdx.x & 63;
    const int row = blockIdx.x * 4 + wave;
    const float4* rp = reinterpret_cast<const float4*>(tbl + (long)row * Eq + lane * 8);
    const float4 v0 = rp[0], v1 = rp[1];

    float s[Cq];
#pragma unroll
    for (int c = 0; c < Cq; ++c) {
        const float4* pp = reinterpret_cast<const float4*>(Pt + c * Eq + lane * 8);
        const float4 p0 = pp[0], p1 = pp[1];
        s[c] = v0.x * p0.x + v0.y * p0.y + v0.z * p0.z + v0.w * p0.w
             + v1.x * p1.x + v1.y * p1.y + v1.z * p1.z + v1.w * p1.w;
    }
#pragma unroll
    for (int m = 1; m < 64; m <<= 1) {
        s[0] += __shfl_xor(s[0], m, 64);
        s[1] += __shfl_xor(s[1], m, 64);
        s[2] += __shfl_xor(s[2], m, 64);
    }
    if (lane < 3) EP[(long)row * 4 + lane] = s[lane];
}

// ---------------- K2: XW = table @ W^T ----------------
// grid dim3(4, 500): x = N-tile (128 cols), y = M-tile (64 vocab rows). 256 thr, 4 waves.
// Wave w: cols [n0+32w, n0+32w+32), all 64 rows -> acc[4][2].
// A reg-staged f32->bf16 swizzled LDS dbuf; B global_load_lds pre-swizzled dbuf.
__global__ __launch_bounds__(256, 3) void xw_kernel(const float* __restrict__ tbl,
                                                    const unsigned short* __restrict__ Wb,
                                                    unsigned short* __restrict__ XW) {
    __shared__ __align__(16) char Abuf[2][8192];    // [64 rows][128B], swizzled
    __shared__ __align__(16) char Bbuf[2][16384];   // [128 cols][128B], swizzled

    const int tid = threadIdx.x;
    const int wave = tid >> 6;
    const int lane = tid & 63;
    const int lr = lane & 15;
    const int lg = lane >> 4;
    const int m0 = (int)blockIdx.y << 6;
    const int n0 = (int)blockIdx.x << 7;
    const int srow = tid >> 3;      // 0..31
    const int sslot = tid & 7;

    const char* WbB = reinterpret_cast<const char*>(Wb);
    float4 a_regs[2][2];

#define ISSUE_A(kb_)                                                               \
    {                                                                              \
        _Pragma("unroll")                                                          \
        for (int p = 0; p < 2; ++p) {                                              \
            const int row = p * 32 + srow;                                         \
            const int g = sslot ^ (row & 7);                                       \
            const float* s = tbl + (long)(m0 + row) * Eq + (kb_) * 64 + g * 8;     \
            a_regs[p][0] = reinterpret_cast<const float4*>(s)[0];                  \
            a_regs[p][1] = reinterpret_cast<const float4*>(s)[1];                  \
        }                                                                          \
    }
#define ISSUE_B(kb_, buf_)                                                         \
    {                                                                              \
        _Pragma("unroll")                                                          \
        for (int q = 0; q < 4; ++q) {                                              \
            const int row = q * 32 + srow;                                         \
            const int g = sslot ^ (row & 7);                                       \
            __builtin_amdgcn_global_load_lds(                                      \
                (const __attribute__((address_space(1))) void*)(WbB +              \
                    (long)(n0 + row) * 1024 + (kb_) * 128 + g * 16),               \
                (__attribute__((address_space(3))) void*)(Bbuf[buf_] + q * 4096 + tid * 16), \
                16, 0, 0);                                                         \
        }                                                                          \
    }
#define WRITE_A(buf_)                                                              \
    {                                                                              \
        _Pragma("unroll")                                                          \
        for (int p = 0; p < 2; ++p) {                                              \
            const int row = p * 32 + srow;                                         \
            uint4 o;                                                               \
            o.x = cvt_pk_bf16(a_regs[p][0].x, a_regs[p][0].y);                     \
            o.y = cvt_pk_bf16(a_regs[p][0].z, a_regs[p][0].w);                     \
            o.z = cvt_pk_bf16(a_regs[p][1].x, a_regs[p][1].y);                     \
            o.w = cvt_pk_bf16(a_regs[p][1].z, a_regs[p][1].w);                     \
            *reinterpret_cast<uint4*>(Abuf[buf_] + row * 128 + sslot * 16) = o;    \
        }                                                                          \
    }

    f32x4 acc[4][2];
#pragma unroll
    for (int i = 0; i < 4; ++i)
#pragma unroll
        for (int j = 0; j < 2; ++j) acc[i][j] = (f32x4){0.f, 0.f, 0.f, 0.f};

    ISSUE_A(0);
    ISSUE_B(0, 0);
    WRITE_A(0);
    __syncthreads();

#pragma unroll
    for (int kb = 0; kb < 8; ++kb) {
        const int cur = kb & 1;
        if (kb < 7) {
            ISSUE_A(kb + 1);
            ISSUE_B(kb + 1, cur ^ 1);
        }
#pragma unroll
        for (int ks = 0; ks < 2; ++ks) {
            bf16x8 af[4], bfv[2];
#pragma unroll
            for (int mf = 0; mf < 4; ++mf) {
                const int r = mf * 16 + lr;
                af[mf] = *reinterpret_cast<const bf16x8*>(
                    Abuf[cur] + r * 128 + ((ks * 64 + lg * 16) ^ ((r & 7) << 4)));
            }
#pragma unroll
            for (int nf = 0; nf < 2; ++nf) {
                const int c = wave * 32 + nf * 16 + lr;
                bfv[nf] = *reinterpret_cast<const bf16x8*>(
                    Bbuf[cur] + c * 128 + ((ks * 64 + lg * 16) ^ ((c & 7) << 4)));
            }
#pragma unroll
            for (int mf = 0; mf < 4; ++mf)
#pragma unroll
                for (int nf = 0; nf < 2; ++nf)
                    acc[mf][nf] = __builtin_amdgcn_mfma_f32_16x16x32_bf16(af[mf], bfv[nf], acc[mf][nf], 0, 0, 0);
        }
        if (kb < 7) {
            WRITE_A(cur ^ 1);
            __syncthreads();
        }
    }

#pragma unroll
    for (int mf = 0; mf < 4; ++mf)
#pragma unroll
        for (int i = 0; i < 4; ++i) {
            const int row = m0 + mf * 16 + (lg << 2) + i;
#pragma unroll
            for (int nf = 0; nf < 2; ++nf) {
                const int col = n0 + wave * 32 + nf * 16 + lr;
                XW[(long)row * Eq + col] = f2bf(acc[mf][nf][i]);
            }
        }
#undef ISSUE_A
#undef ISSUE_B
#undef WRITE_A
}

// ---------------- K3: gather + combine + bias + LayerNorm + swish ----------------
// grid = M/8 = 4096 blocks, 512 threads (8 waves), wave per token.
__global__ __launch_bounds__(512, 4) void gather_kernel(const int* __restrict__ tokens,
                                                        const unsigned short* __restrict__ XW,
                                                        const float* __restrict__ EP,
                                                        const float* __restrict__ bias,
                                                        const float* __restrict__ ln_g,
                                                        const float* __restrict__ ln_b,
                                                        float* __restrict__ out) {
    const int wave = threadIdx.x >> 6;
    const int lane = threadIdx.x & 63;
    const int tt = blockIdx.x * 8 + wave;   // 0..M-1
    const int t = tt & (Tq - 1);
    const int e0 = lane * 8;

    float v[8];
#pragma unroll
    for (int j = 0; j < 8; ++j) v[j] = 0.f;

#pragma unroll
    for (int c = 0; c < Cq; ++c) {
        if (t + c >= 2) {                         // token t-2+c exists
            const int tok = tokens[tt + c - 2];
            const float s = EP[(long)tok * 4 + c];
            const bf16x8 xv = *reinterpret_cast<const bf16x8*>(XW + (long)tok * Eq + e0);
#pragma unroll
            for (int j = 0; j < 8; ++j)
                v[j] += s * bf2f((unsigned short)xv[j]);
        }
    }

    const float inv = 1.f / (Hq * Cq);
    const float4* bp = reinterpret_cast<const float4*>(bias + e0);
    const float4 b0 = bp[0], b1 = bp[1];
    float o[8];
    o[0] = v[0] * inv + b0.x; o[1] = v[1] * inv + b0.y;
    o[2] = v[2] * inv + b0.z; o[3] = v[3] * inv + b0.w;
    o[4] = v[4] * inv + b1.x; o[5] = v[5] * inv + b1.y;
    o[6] = v[6] * inv + b1.z; o[7] = v[7] * inv + b1.w;

    float sm = 0.f, sq = 0.f;
#pragma unroll
    for (int j = 0; j < 8; ++j) { sm += o[j]; sq += o[j] * o[j]; }
#pragma unroll
    for (int m = 1; m < 64; m <<= 1) {
        sm += __shfl_xor(sm, m, 64);
        sq += __shfl_xor(sq, m, 64);
    }
    const float mu = sm * (1.f / Eq);
    const float var = sq * (1.f / Eq) - mu * mu;
    const float rs = rsqrtf(var + LN_EPS);

    const float4* gp = reinterpret_cast<const float4*>(ln_g + e0);
    const float4* lp = reinterpret_cast<const float4*>(ln_b + e0);
    const float4 g0 = gp[0], g1 = gp[1];
    const float4 l0 = lp[0], l1 = lp[1];
    float gg[8] = {g0.x, g0.y, g0.z, g0.w, g1.x, g1.y, g1.z, g1.w};
    float ll[8] = {l0.x, l0.y, l0.z, l0.w, l1.x, l1.y, l1.z, l1.w};

    float4 r0, r1;
    float* rr0 = reinterpret_cast<float*>(&r0);
    float* rr1 = reinterpret_cast<float*>(&r1);
#pragma unroll
    for (int j = 0; j < 8; ++j) {
        float y = (o[j] - mu) * rs * gg[j] + ll[j];
        y = y / (1.f + __expf(-y));   // swish
        if (j < 4) rr0[j] = y; else rr1[j - 4] = y;
    }
    float4* op = reinterpret_cast<float4*>(out + (long)tt * Eq + e0);
    op[0] = r0;
    op[1] = r1;
}

extern "C" void kernel_launch(void* const* d_in, const int* in_sizes, int n_in,
                              void* d_out, int out_size, void* d_ws, size_t ws_size,
                              hipStream_t stream) {
    const int* tokens = (const int*)d_in[0];
    const float* tbl = (const float*)d_in[1];
    const float* pos = (const float*)d_in[2];
    const float* ffn_w = (const float*)d_in[3];
    const float* ffn_b = (const float*)d_in[4];
    const float* ln_g = (const float*)d_in[5];
    const float* ln_b = (const float*)d_in[6];
    float* out = (float*)d_out;

    char* ws = (char*)d_ws;
    float* Pt = (float*)ws;                                   // 8 KB
    unsigned short* Wb = (unsigned short*)(ws + 16384);       // 512 KB
    float* EP = (float*)(ws + (1 << 20));                     // 512 KB
    unsigned short* XW = (unsigned short*)(ws + (2 << 20));   // 32.8 MB

    hipLaunchKernelGGL(prep_kernel, dim3(64), dim3(256), 0, stream, pos, ffn_w, Pt, Wb);
    hipLaunchKernelGGL(ep_kernel, dim3(Vq / 4), dim3(256), 0, stream, tbl, Pt, EP);
    hipLaunchKernelGGL(xw_kernel, dim3(4, Vq / 64), dim3(256), 0, stream, tbl, Wb, XW);
    hipLaunchKernelGGL(gather_kernel, dim3(Mq / 8), dim3(512), 0, stream,
                       tokens, XW, EP, ffn_b, ln_g, ln_b, out);
}